// Round 7
// baseline (46.257 us; speedup 1.0000x reference)
//
#include <hip/hip_runtime.h>
#include <math.h>
#include <stdint.h>

// BettingLoss: scalar loss over B=1048576 races, T=8 dogs.
// Inputs (float32, each B*T): predicted_probs, true_winners(one-hot),
// market_odds, gumbel_noise. Output: 1 float32 scalar.
//
// R6: R0's two-kernel structure (best replay 35.5us) with the loads
// replaced by an inline-asm block issuing 16 global_load_dwordx4
// back-to-back + one s_waitcnt vmcnt(0) INSIDE the asm. R0-R5 all show
// VGPR<=36 => compiler serialized loads into 2-3 groups per race,
// exposing L3 latency repeatedly; sched_barrier(0) failed to stop it.
// Asm outputs are early-clobber float4s => 64 dest VGPRs live, 16 loads
// in flight per wave, guaranteed. Values final at asm end (no separate
// waitcnt => no hoisting hazard).

constexpr int T = 8;
constexpr int NB = 1024;
constexpr int NT = 256;

__device__ __forceinline__ float fastrcp(float x) {
  return __builtin_amdgcn_rcpf(x);
}

// acc: 0=cnt, 1=sum(ce*valid), 2=sum(ce), 3=sum(soft_ep*valid),
//      4=sum(max_prob), 5=sum(entropy)
__device__ __forceinline__ void compute_race(
    const float4& A0, const float4& A1, const float4& W0, const float4& W1,
    const float4& O0, const float4& O1, const float4& G0, const float4& G1,
    float acc[6]) {
  float p[T] = {A0.x, A0.y, A0.z, A0.w, A1.x, A1.y, A1.z, A1.w};
  float w[T] = {W0.x, W0.y, W0.z, W0.w, W1.x, W1.y, W1.z, W1.w};
  float o[T] = {O0.x, O0.y, O0.z, O0.w, O1.x, O1.y, O1.z, O1.w};
  float g[T] = {G0.x, G0.y, G0.z, G0.w, G1.x, G1.y, G1.z, G1.w};

  // validity
  bool anypos = false;
  float simp = 0.f;
#pragma unroll
  for (int t = 0; t < T; ++t) {
    anypos = anypos || (o[t] > 0.f);
    simp += fastrcp(fmaxf(o[t], 1.01f));
  }
  float vf = (anypos && simp >= 0.95f) ? 1.f : 0.f;

  // expected profit (vf-masked; only vf-weighted terms consume it)
  float ep[T];
#pragma unroll
  for (int t = 0; t < T; ++t)
    ep[t] = (o[t] * 1.1f * p[t] - 1.f) * (0.02f * 0.95f) * vf;

  // gumbel-softmax selection: softmax(ep*100 + g*10)
  float z[T], zm = -INFINITY;
#pragma unroll
  for (int t = 0; t < T; ++t) {
    z[t] = ep[t] * 100.f + g[t] * 10.f;
    zm = fmaxf(zm, z[t]);
  }
  float s2 = 0.f, sp = 0.f;
#pragma unroll
  for (int t = 0; t < T; ++t) {
    float e = __expf(z[t] - zm);
    s2 += e;
    sp += e * ep[t];
  }
  float soft_ep = sp * fastrcp(s2);

  // cross-entropy (probs as logits), one-hot label
  float m = -INFINITY;
#pragma unroll
  for (int t = 0; t < T; ++t) m = fmaxf(m, p[t]);
  float se = 0.f, pl = 0.f;
#pragma unroll
  for (int t = 0; t < T; ++t) {
    se += __expf(p[t] - m);
    pl += w[t] * p[t];
  }
  float ce = m + __logf(se) - pl;

  // entropy
  float ent = 0.f;
#pragma unroll
  for (int t = 0; t < T; ++t) ent -= p[t] * __logf(p[t] + 1e-8f);

  acc[0] += vf;
  acc[1] += ce * vf;
  acc[2] += ce;
  acc[3] += soft_ep * vf;
  acc[4] += m;
  acc[5] += ent;
}

__device__ __forceinline__ void block_reduce_publish(
    float acc[6], float* __restrict__ partials) {
  __shared__ float red[NT / 64][6];
#pragma unroll
  for (int k = 0; k < 6; ++k) {
#pragma unroll
    for (int off = 32; off >= 1; off >>= 1) acc[k] += __shfl_down(acc[k], off);
  }
  int lane = threadIdx.x & 63, wave = threadIdx.x >> 6;
  if (lane == 0) {
#pragma unroll
    for (int k = 0; k < 6; ++k) red[wave][k] = acc[k];
  }
  __syncthreads();
  if (threadIdx.x == 0) {
#pragma unroll
    for (int k = 0; k < 6; ++k) {
      float s = red[0][k] + red[1][k] + red[2][k] + red[3][k];
      partials[k * gridDim.x + blockIdx.x] = s;  // SoA for coalesced finalize
    }
  }
}

// exact path: nraces == 4 * gridDim.x * NT. Two batches; each batch
// issues 16 dwordx4 loads (2 races) in one asm block, waits once.
__global__ __launch_bounds__(NT, 4) void betting_asm(
    const float4* __restrict__ pp4, const float4* __restrict__ tw4,
    const float4* __restrict__ mo4, const float4* __restrict__ gn4,
    float* __restrict__ partials) {
  const int tid = blockIdx.x * NT + threadIdx.x;
  const int ntot = gridDim.x * NT;

  float acc[6] = {0.f, 0.f, 0.f, 0.f, 0.f, 0.f};

#pragma unroll
  for (int batch = 0; batch < 2; ++batch) {
    const int ra = tid + (2 * batch) * ntot;
    const int rb = tid + (2 * batch + 1) * ntot;

    uint64_t pa = (uint64_t)(pp4 + 2 * ra);
    uint64_t pb = (uint64_t)(tw4 + 2 * ra);
    uint64_t pc = (uint64_t)(mo4 + 2 * ra);
    uint64_t pd = (uint64_t)(gn4 + 2 * ra);
    uint64_t qa = (uint64_t)(pp4 + 2 * rb);
    uint64_t qb = (uint64_t)(tw4 + 2 * rb);
    uint64_t qc = (uint64_t)(mo4 + 2 * rb);
    uint64_t qd = (uint64_t)(gn4 + 2 * rb);

    float4 a0, a1, b0, b1, c0, c1, d0, d1;   // race ra
    float4 e0, e1, f0, f1, g0, g1, h0, h1;   // race rb
    asm volatile(
        "global_load_dwordx4 %0, %16, off\n\t"
        "global_load_dwordx4 %1, %16, off offset:16\n\t"
        "global_load_dwordx4 %2, %17, off\n\t"
        "global_load_dwordx4 %3, %17, off offset:16\n\t"
        "global_load_dwordx4 %4, %18, off\n\t"
        "global_load_dwordx4 %5, %18, off offset:16\n\t"
        "global_load_dwordx4 %6, %19, off\n\t"
        "global_load_dwordx4 %7, %19, off offset:16\n\t"
        "global_load_dwordx4 %8, %20, off\n\t"
        "global_load_dwordx4 %9, %20, off offset:16\n\t"
        "global_load_dwordx4 %10, %21, off\n\t"
        "global_load_dwordx4 %11, %21, off offset:16\n\t"
        "global_load_dwordx4 %12, %22, off\n\t"
        "global_load_dwordx4 %13, %22, off offset:16\n\t"
        "global_load_dwordx4 %14, %23, off\n\t"
        "global_load_dwordx4 %15, %23, off offset:16\n\t"
        "s_waitcnt vmcnt(0)"
        : "=&v"(a0), "=&v"(a1), "=&v"(b0), "=&v"(b1),
          "=&v"(c0), "=&v"(c1), "=&v"(d0), "=&v"(d1),
          "=&v"(e0), "=&v"(e1), "=&v"(f0), "=&v"(f1),
          "=&v"(g0), "=&v"(g1), "=&v"(h0), "=&v"(h1)
        : "v"(pa), "v"(pb), "v"(pc), "v"(pd),
          "v"(qa), "v"(qb), "v"(qc), "v"(qd));

    compute_race(a0, a1, b0, b1, c0, c1, d0, d1, acc);
    compute_race(e0, e1, f0, f1, g0, g1, h0, h1, acc);
  }

  block_reduce_publish(acc, partials);
}

// generic fallback: any nraces (plain grid-stride, compiler-scheduled loads)
__global__ __launch_bounds__(NT, 4) void betting_generic(
    const float4* __restrict__ pp4, const float4* __restrict__ tw4,
    const float4* __restrict__ mo4, const float4* __restrict__ gn4,
    float* __restrict__ partials, int nraces) {
  const int tid = blockIdx.x * NT + threadIdx.x;
  const int ntot = gridDim.x * NT;

  float acc[6] = {0.f, 0.f, 0.f, 0.f, 0.f, 0.f};
  for (int r = tid; r < nraces; r += ntot) {
    float4 a0 = pp4[2 * r], a1 = pp4[2 * r + 1];
    float4 b0 = tw4[2 * r], b1 = tw4[2 * r + 1];
    float4 c0 = mo4[2 * r], c1 = mo4[2 * r + 1];
    float4 d0 = gn4[2 * r], d1 = gn4[2 * r + 1];
    compute_race(a0, a1, b0, b1, c0, c1, d0, d1, acc);
  }
  block_reduce_publish(acc, partials);
}

__global__ __launch_bounds__(NT) void betting_final(
    const float* __restrict__ partials, int nb, float* __restrict__ out,
    double Bd) {
  __shared__ double red[NT / 64][6];
  double a[6] = {0, 0, 0, 0, 0, 0};
#pragma unroll
  for (int k = 0; k < 6; ++k)
    for (int i = threadIdx.x; i < nb; i += NT) a[k] += (double)partials[k * nb + i];
#pragma unroll
  for (int k = 0; k < 6; ++k) {
#pragma unroll
    for (int off = 32; off >= 1; off >>= 1) a[k] += __shfl_down(a[k], off);
  }
  int lane = threadIdx.x & 63, wave = threadIdx.x >> 6;
  if (lane == 0) {
#pragma unroll
    for (int k = 0; k < 6; ++k) red[wave][k] = a[k];
  }
  __syncthreads();
  if (threadIdx.x == 0) {
    double s[6];
#pragma unroll
    for (int k = 0; k < 6; ++k)
      s[k] = red[0][k] + red[1][k] + red[2][k] + red[3][k];
    double cnt = s[0], Scev = s[1], Sce = s[2], Ssoft = s[3], Smax = s[4],
           Sent = s[5];
    double pred = (cnt > 0.0) ? Scev / fmax(cnt, 1.0) : Sce / Bd;
    double conf = -(Smax / Bd) * 0.1;
    double bet = (cnt > 0.0) ? -Ssoft / Bd : conf;
    double entr = Sent / Bd;
    double lam = fmin(0.5 + cnt / 10000.0 * 0.5, 1.0);
    out[0] = (float)(pred + lam * bet - 0.01 * entr);
  }
}

extern "C" void kernel_launch(void* const* d_in, const int* in_sizes, int n_in,
                              void* d_out, int out_size, void* d_ws,
                              size_t ws_size, hipStream_t stream) {
  const float4* pp = (const float4*)d_in[0];
  const float4* tw = (const float4*)d_in[1];
  const float4* mo = (const float4*)d_in[2];
  const float4* gn = (const float4*)d_in[3];
  float* out = (float*)d_out;
  float* partials = (float*)d_ws;

  const int nraces = in_sizes[0] / T;

  int nb = NB;
  while ((size_t)(6 * nb * 4) > ws_size && nb > 64) nb >>= 1;

  if (nraces == 4 * nb * NT) {
    betting_asm<<<nb, NT, 0, stream>>>(pp, tw, mo, gn, partials);
  } else {
    betting_generic<<<nb, NT, 0, stream>>>(pp, tw, mo, gn, partials, nraces);
  }
  betting_final<<<1, NT, 0, stream>>>(partials, nb, out, (double)nraces);
}

// Round 8
// 36.395 us; speedup vs baseline: 1.2710x; 1.2710x over previous
//
#include <hip/hip_runtime.h>
#include <math.h>
#include <stdint.h>

// BettingLoss: scalar loss over B=1048576 races, T=8 dogs.
// Inputs (float32, each B*T): predicted_probs, true_winners(one-hot),
// market_odds, gumbel_noise. Output: 1 float32 scalar.
//
// R8: global_load_lds staging pipeline. R0-R7 showed the main loop is
// stuck at ~4.3 TB/s from L3 regardless of occupancy/coalescing/hints;
// every attempt to force register-MLP failed (compiler sink, or spill:
// R7's 16-float4 asm spilled 32MB to scratch). global_load_lds issues
// loads with NO destination VGPRs, counted s_waitcnt vmcnt(4) keeps one
// chunk always in flight, LDS double-buffer (per-wave private, zero
// barriers) holds the data. Consumption: lane l reads byte l*16 of each
// staged 1KB array span (m134 conflict-free ds_read_b128 pattern); lane
// pairs 2k/2k+1 split race k and combine via shfl_xor(.,1) — the R2
// half-race compute, which validated absmax=0.

constexpr int T = 8;
constexpr int NT = 256;
constexpr int WAVES = NT / 64;                           // 4
constexpr int RACES_PER_BLOCK = 1024;
constexpr int RACES_PER_WAVE = RACES_PER_BLOCK / WAVES;  // 256
constexpr int CHUNK_RACES = 32;                          // per wave per chunk
constexpr int NCHUNK = RACES_PER_WAVE / CHUNK_RACES;     // 8
constexpr int CHUNK_B = CHUNK_RACES * 32;                // 1024 B per array

typedef const __attribute__((address_space(1))) void gas_t;
typedef __attribute__((address_space(3))) void las_t;

__device__ __forceinline__ float fastrcp(float x) {
  return __builtin_amdgcn_rcpf(x);
}

__device__ __forceinline__ void block_reduce_publish(
    float acc[6], float* __restrict__ partials) {
  __shared__ float red[WAVES][6];
#pragma unroll
  for (int k = 0; k < 6; ++k) {
#pragma unroll
    for (int off = 32; off >= 1; off >>= 1) acc[k] += __shfl_down(acc[k], off);
  }
  const int lane = threadIdx.x & 63, wave = threadIdx.x >> 6;
  if (lane == 0) {
#pragma unroll
    for (int k = 0; k < 6; ++k) red[wave][k] = acc[k];
  }
  __syncthreads();
  if (threadIdx.x == 0) {
#pragma unroll
    for (int k = 0; k < 6; ++k) {
      float s = red[0][k] + red[1][k] + red[2][k] + red[3][k];
      partials[k * gridDim.x + blockIdx.x] = s;  // SoA for coalesced finalize
    }
  }
}

// acc: 0=cnt, 1=sum(ce*valid), 2=sum(ce), 3=sum(soft_ep*valid),
//      4=sum(max_prob), 5=sum(entropy)   (all via 0.5-weighted half-races)
__global__ __launch_bounds__(NT, 4) void betting_lds(
    const char* __restrict__ pp, const char* __restrict__ tw,
    const char* __restrict__ mo, const char* __restrict__ gn,
    float* __restrict__ partials) {
  __shared__ uint8_t stg[WAVES][2][4][CHUNK_B];  // 32 KB
  const int wave = threadIdx.x >> 6, lane = threadIdx.x & 63;

  const long base0 =
      ((long)blockIdx.x * RACES_PER_BLOCK + (long)wave * RACES_PER_WAVE) * 32;
  const char* ga0 = pp + base0;
  const char* ga1 = tw + base0;
  const char* ga2 = mo + base0;
  const char* ga3 = gn + base0;

  float acc[6] = {0.f, 0.f, 0.f, 0.f, 0.f, 0.f};

  auto stage = [&](int j, int buf) {
    const long off = (long)j * CHUNK_B + (long)lane * 16;
    __builtin_amdgcn_global_load_lds((gas_t*)(ga0 + off),
                                     (las_t*)&stg[wave][buf][0][0], 16, 0, 0);
    __builtin_amdgcn_global_load_lds((gas_t*)(ga1 + off),
                                     (las_t*)&stg[wave][buf][1][0], 16, 0, 0);
    __builtin_amdgcn_global_load_lds((gas_t*)(ga2 + off),
                                     (las_t*)&stg[wave][buf][2][0], 16, 0, 0);
    __builtin_amdgcn_global_load_lds((gas_t*)(ga3 + off),
                                     (las_t*)&stg[wave][buf][3][0], 16, 0, 0);
  };

  auto consume = [&](int buf) {
    const int lb = lane * 16;
    float4 av = *(const float4*)&stg[wave][buf][0][lb];
    float4 wv = *(const float4*)&stg[wave][buf][1][lb];
    float4 ov = *(const float4*)&stg[wave][buf][2][lb];
    float4 gv = *(const float4*)&stg[wave][buf][3][lb];
    float p[4] = {av.x, av.y, av.z, av.w};
    float w[4] = {wv.x, wv.y, wv.z, wv.w};
    float o[4] = {ov.x, ov.y, ov.z, ov.w};
    float g[4] = {gv.x, gv.y, gv.z, gv.w};

    // validity (race-wide via pair shuffle)
    float anyp = 0.f, simp = 0.f;
#pragma unroll
    for (int t = 0; t < 4; ++t) {
      anyp = fmaxf(anyp, (o[t] > 0.f) ? 1.f : 0.f);
      simp += fastrcp(fmaxf(o[t], 1.01f));
    }
    anyp = fmaxf(anyp, __shfl_xor(anyp, 1));
    simp = simp + __shfl_xor(simp, 1);
    float vf = (anyp > 0.5f && simp >= 0.95f) ? 1.f : 0.f;

    // masked expected profit
    float ep[4];
#pragma unroll
    for (int t = 0; t < 4; ++t)
      ep[t] = (o[t] * 1.1f * p[t] - 1.f) * (0.02f * 0.95f) * vf;

    // gumbel-softmax selection over 8 dogs
    float z[4], zmh = -INFINITY;
#pragma unroll
    for (int t = 0; t < 4; ++t) {
      z[t] = ep[t] * 100.f + g[t] * 10.f;
      zmh = fmaxf(zmh, z[t]);
    }
    float zm = fmaxf(zmh, __shfl_xor(zmh, 1));
    float s2h = 0.f, sph = 0.f;
#pragma unroll
    for (int t = 0; t < 4; ++t) {
      float e = __expf(z[t] - zm);
      s2h += e;
      sph += e * ep[t];
    }
    float s2 = s2h + __shfl_xor(s2h, 1);
    float sp = sph + __shfl_xor(sph, 1);
    float soft_ep = sp * fastrcp(s2);

    // cross-entropy (probs as logits)
    float mh = fmaxf(fmaxf(p[0], p[1]), fmaxf(p[2], p[3]));
    float m = fmaxf(mh, __shfl_xor(mh, 1));
    float seh = 0.f, plh = 0.f;
#pragma unroll
    for (int t = 0; t < 4; ++t) {
      seh += __expf(p[t] - m);
      plh += w[t] * p[t];
    }
    float se = seh + __shfl_xor(seh, 1);
    float celin = 0.5f * (m + __logf(se)) - plh;  // pair-sum = full ce

    // entropy (linear, per-half)
    float enth = 0.f;
#pragma unroll
    for (int t = 0; t < 4; ++t) enth -= p[t] * __logf(p[t] + 1e-8f);

    acc[0] += 0.5f * vf;
    acc[1] += celin * vf;
    acc[2] += celin;
    acc[3] += 0.5f * soft_ep * vf;
    acc[4] += 0.5f * m;
    acc[5] += enth;
  };

  stage(0, 0);
  for (int j = 0; j < NCHUNK - 1; ++j) {
    stage(j + 1, (j + 1) & 1);
    asm volatile("s_waitcnt vmcnt(4)" ::: "memory");  // chunk j's 4 done
    __builtin_amdgcn_sched_barrier(0);
    consume(j & 1);
  }
  asm volatile("s_waitcnt vmcnt(0)" ::: "memory");
  __builtin_amdgcn_sched_barrier(0);
  consume((NCHUNK - 1) & 1);

  block_reduce_publish(acc, partials);
}

// generic fallback (R0 structure) for sizes not divisible by RACES_PER_BLOCK
__global__ __launch_bounds__(NT, 4) void betting_generic(
    const float4* __restrict__ pp4, const float4* __restrict__ tw4,
    const float4* __restrict__ mo4, const float4* __restrict__ gn4,
    float* __restrict__ partials, int nraces) {
  const int tid = blockIdx.x * NT + threadIdx.x;
  const int ntot = gridDim.x * NT;

  float acc[6] = {0.f, 0.f, 0.f, 0.f, 0.f, 0.f};
  for (int r = tid; r < nraces; r += ntot) {
    float4 a0 = pp4[2 * r], a1 = pp4[2 * r + 1];
    float4 b0 = tw4[2 * r], b1 = tw4[2 * r + 1];
    float4 c0 = mo4[2 * r], c1 = mo4[2 * r + 1];
    float4 d0 = gn4[2 * r], d1 = gn4[2 * r + 1];
    float p[T] = {a0.x, a0.y, a0.z, a0.w, a1.x, a1.y, a1.z, a1.w};
    float w[T] = {b0.x, b0.y, b0.z, b0.w, b1.x, b1.y, b1.z, b1.w};
    float o[T] = {c0.x, c0.y, c0.z, c0.w, c1.x, c1.y, c1.z, c1.w};
    float g[T] = {d0.x, d0.y, d0.z, d0.w, d1.x, d1.y, d1.z, d1.w};

    bool anypos = false;
    float simp = 0.f;
#pragma unroll
    for (int t = 0; t < T; ++t) {
      anypos = anypos || (o[t] > 0.f);
      simp += fastrcp(fmaxf(o[t], 1.01f));
    }
    float vf = (anypos && simp >= 0.95f) ? 1.f : 0.f;

    float ep[T];
#pragma unroll
    for (int t = 0; t < T; ++t)
      ep[t] = (o[t] * 1.1f * p[t] - 1.f) * (0.02f * 0.95f) * vf;

    float z[T], zm = -INFINITY;
#pragma unroll
    for (int t = 0; t < T; ++t) {
      z[t] = ep[t] * 100.f + g[t] * 10.f;
      zm = fmaxf(zm, z[t]);
    }
    float s2 = 0.f, sp = 0.f;
#pragma unroll
    for (int t = 0; t < T; ++t) {
      float e = __expf(z[t] - zm);
      s2 += e;
      sp += e * ep[t];
    }
    float soft_ep = sp * fastrcp(s2);

    float m = -INFINITY;
#pragma unroll
    for (int t = 0; t < T; ++t) m = fmaxf(m, p[t]);
    float se = 0.f, pl = 0.f;
#pragma unroll
    for (int t = 0; t < T; ++t) {
      se += __expf(p[t] - m);
      pl += w[t] * p[t];
    }
    float ce = m + __logf(se) - pl;

    float ent = 0.f;
#pragma unroll
    for (int t = 0; t < T; ++t) ent -= p[t] * __logf(p[t] + 1e-8f);

    acc[0] += vf;
    acc[1] += ce * vf;
    acc[2] += ce;
    acc[3] += soft_ep * vf;
    acc[4] += m;
    acc[5] += ent;
  }
  block_reduce_publish(acc, partials);
}

__global__ __launch_bounds__(NT) void betting_final(
    const float* __restrict__ partials, int nb, float* __restrict__ out,
    double Bd) {
  __shared__ double red[NT / 64][6];
  double a[6] = {0, 0, 0, 0, 0, 0};
#pragma unroll
  for (int k = 0; k < 6; ++k)
    for (int i = threadIdx.x; i < nb; i += NT) a[k] += (double)partials[k * nb + i];
#pragma unroll
  for (int k = 0; k < 6; ++k) {
#pragma unroll
    for (int off = 32; off >= 1; off >>= 1) a[k] += __shfl_down(a[k], off);
  }
  int lane = threadIdx.x & 63, wave = threadIdx.x >> 6;
  if (lane == 0) {
#pragma unroll
    for (int k = 0; k < 6; ++k) red[wave][k] = a[k];
  }
  __syncthreads();
  if (threadIdx.x == 0) {
    double s[6];
#pragma unroll
    for (int k = 0; k < 6; ++k)
      s[k] = red[0][k] + red[1][k] + red[2][k] + red[3][k];
    double cnt = s[0], Scev = s[1], Sce = s[2], Ssoft = s[3], Smax = s[4],
           Sent = s[5];
    double pred = (cnt > 0.0) ? Scev / fmax(cnt, 1.0) : Sce / Bd;
    double conf = -(Smax / Bd) * 0.1;
    double bet = (cnt > 0.0) ? -Ssoft / Bd : conf;
    double entr = Sent / Bd;
    double lam = fmin(0.5 + cnt / 10000.0 * 0.5, 1.0);
    out[0] = (float)(pred + lam * bet - 0.01 * entr);
  }
}

extern "C" void kernel_launch(void* const* d_in, const int* in_sizes, int n_in,
                              void* d_out, int out_size, void* d_ws,
                              size_t ws_size, hipStream_t stream) {
  const char* pp = (const char*)d_in[0];
  const char* tw = (const char*)d_in[1];
  const char* mo = (const char*)d_in[2];
  const char* gn = (const char*)d_in[3];
  float* out = (float*)d_out;
  float* partials = (float*)d_ws;

  const int nraces = in_sizes[0] / T;

  if (nraces > 0 && nraces % RACES_PER_BLOCK == 0 &&
      (size_t)(6 * (nraces / RACES_PER_BLOCK) * 4) <= ws_size &&
      nraces / RACES_PER_BLOCK <= 65535) {
    const int nb = nraces / RACES_PER_BLOCK;  // 1024 for B=1M
    betting_lds<<<nb, NT, 0, stream>>>(pp, tw, mo, gn, partials);
    betting_final<<<1, NT, 0, stream>>>(partials, nb, out, (double)nraces);
  } else {
    int nb = 1024;
    while ((size_t)(6 * nb * 4) > ws_size && nb > 64) nb >>= 1;
    betting_generic<<<nb, NT, 0, stream>>>(
        (const float4*)pp, (const float4*)tw, (const float4*)mo,
        (const float4*)gn, partials, nraces);
    betting_final<<<1, NT, 0, stream>>>(partials, nb, out, (double)nraces);
  }
}